// Round 14
// baseline (76.801 us; speedup 1.0000x reference)
//
#include <hip/hip_runtime.h>
#include <hip/hip_bf16.h>

// BarlowTwins loss: logits[b,n,m] = sum_s z1[b,s,n]*z2[b,s,m]  (B=8, S=256, N=M=2048)
// loss = mean_{b,m}( LSE_n(logits[b,:,m]) - logits[b,m,m] )
//
// Round-14 = R11 (30.1us best: block 512m x 256n, wave owns 64m (2 strips, bf 128 regs)
// x full 256n, reg-staged f32->bf16->LDS stride 264, exp2-sum no max tracking)
// + (1) amdgpu_waves_per_eu(2,2): pin allocator occupancy target to the 2 waves/SIMD the
//   1-block/CU grid actually runs -> 256-VGPR budget (every prior variant chose 128);
// + (2) BN=64 tiles: 4 tiles instead of 8 -> HALF the lockstep barrier drains. The two
//   32-n subtiles of a tile run sequentially (one acc-pair live at a time, no R12
//   pressure); staging for t+1/t+2 issued between subtiles so its VMEM latency hides
//   under subtile-1's MFMA stream.

#define NN 2048
#define SK 256
#define LDST 264
#define LOG2E 1.4426950408889634f
#define LN2   0.6931471805599453f
#define COFF  96.0f

typedef __attribute__((ext_vector_type(8))) short short8;
typedef __attribute__((ext_vector_type(16))) float f32x16;

__device__ __forceinline__ unsigned short f2bf(float f) {
    __hip_bfloat16 h = __float2bfloat16(f);
    unsigned short u; __builtin_memcpy(&u, &h, 2); return u;
}

__device__ __forceinline__ float exp2g(float x) {
#if __has_builtin(__builtin_amdgcn_exp2f)
    return __builtin_amdgcn_exp2f(x);
#else
    return exp2f(x);
#endif
}

__device__ __forceinline__ float log2g(float x) {
#if __has_builtin(__builtin_amdgcn_logf)
    return __builtin_amdgcn_logf(x);
#else
    return log2f(x);
#endif
}

__global__ __launch_bounds__(512)
__attribute__((amdgpu_waves_per_eu(2, 2)))
void gemm_lse_kernel(
    const float* __restrict__ z1, const float* __restrict__ z2,
    float* __restrict__ ws_sum, float* __restrict__ ws_diag)
{
    __shared__ unsigned short lds[2][64 * LDST];   // 2 x 33.8 KB

    const int bid  = blockIdx.x;
    const int b    = bid & 7;          // XCD-aligned batch
    const int tile = bid >> 3;
    const int mb   = tile & 3;         // 4 m-blocks of 512
    const int ns   = tile >> 2;        // 8 n-splits of 256
    const int tid  = threadIdx.x;
    const int lane = tid & 63;
    const int w    = tid >> 6;         // wave 0..7 owns 64 m
    const int col  = lane & 31;
    const int kg   = lane >> 5;

    const int m0      = mb * 512 + w * 64;   // strip0; strip1 = +32
    const int mcol0   = m0 + col;
    const int mcol1   = m0 + 32 + col;
    const int n_start = ns * 256;

    const float* z1b = z1 + (size_t)b * SK * NN;
    const float* z2b = z2 + (size_t)b * SK * NN;

    // ---- A staging: tile = 64 n-rows x 256 k; thread (kc,row) loads 32 f32 ----
    const int kc  = (w << 1) | kg;     // k-chunk 0..15 (16 s each)
    const int row = col;               // n-row within 32-half
    float apf[32];
    auto load_A = [&](int t) {
        #pragma unroll
        for (int h = 0; h < 2; ++h) {
            const float* p = z1b + (size_t)(kc * 16) * NN + (n_start + 64 * t + 32 * h + row);
            #pragma unroll
            for (int j = 0; j < 16; ++j) apf[h * 16 + j] = p[(size_t)j * NN];
        }
    };
    auto store_A = [&](unsigned short* buf) {
        #pragma unroll
        for (int h = 0; h < 2; ++h) {
            short8 pk0, pk1;
            #pragma unroll
            for (int j = 0; j < 8; ++j) {
                pk0[j] = (short)f2bf(apf[h * 16 + j]);
                pk1[j] = (short)f2bf(apf[h * 16 + 8 + j]);
            }
            *(short8*)(buf + (32 * h + row) * LDST + kc * 16)     = pk0;
            *(short8*)(buf + (32 * h + row) * LDST + kc * 16 + 8) = pk1;
        }
    };

    // ---- prologue: B K-half 0, stage tile0, B K-half 1, load tile1 ----
    short8 bf0[16], bf1[16];
    auto loadB = [&](int ks) {
        short8 p0, p1;
        #pragma unroll
        for (int j = 0; j < 8; ++j) {
            const int s = ks * 16 + kg * 8 + j;
            p0[j] = (short)f2bf(z2b[(size_t)s * NN + mcol0] * LOG2E);
            p1[j] = (short)f2bf(z2b[(size_t)s * NN + mcol1] * LOG2E);
        }
        bf0[ks] = p0; bf1[ks] = p1;
    };

    #pragma unroll
    for (int ks = 0; ks < 8; ++ks) loadB(ks);
    load_A(0);
    store_A(lds[0]);
    load_A(1);
    #pragma unroll
    for (int ks = 8; ks < 16; ++ks) loadB(ks);

    float srun0 = 0.0f, srun1 = 0.0f;

    __syncthreads();   // buf0 visible

    for (int t = 0; t < 4; ++t) {
        #pragma unroll
        for (int sub = 0; sub < 2; ++sub) {
            const unsigned short* abase = lds[t & 1] + (32 * sub + col) * LDST + kg * 8;

            f32x16 acc0, acc1;
            #pragma unroll
            for (int r = 0; r < 16; ++r) { acc0[r] = -COFF; acc1[r] = -COFF; }

            #pragma unroll
            for (int ks = 0; ks < 16; ++ks) {
                short8 af = *(const short8*)(abase + ks * 16);
                acc0 = __builtin_amdgcn_mfma_f32_32x32x16_bf16(af, bf0[ks], acc0, 0, 0, 0);
                acc1 = __builtin_amdgcn_mfma_f32_32x32x16_bf16(af, bf1[ks], acc1, 0, 0, 0);
            }

            if (sub == 0) {
                // staging issued between subtiles: VMEM latency hides under sub1 MFMAs
                if (t < 3) store_A(lds[(t + 1) & 1]);   // apf holds tile t+1
                if (t < 2) load_A(t + 2);
            }

            // diagonal capture (acc = logit' - 96; offset cancels in merge)
            const int nsub = n_start + 64 * t + 32 * sub;
            if (nsub == m0) {
                #pragma unroll
                for (int r = 0; r < 16; ++r) {
                    const int rw = (r & 3) + 8 * (r >> 2) + 4 * kg;
                    if (rw == col) ws_diag[b * NN + mcol0] = acc0[r];
                }
            }
            if (nsub == m0 + 32) {
                #pragma unroll
                for (int r = 0; r < 16; ++r) {
                    const int rw = (r & 3) + 8 * (r >> 2) + 4 * kg;
                    if (rw == col) ws_diag[b * NN + mcol1] = acc1[r];
                }
            }

            // exp2-sum, 4 independent chains per strip
            {
                float e0 = 0, e1 = 0, e2 = 0, e3 = 0;
                #pragma unroll
                for (int r = 0; r < 16; r += 4) {
                    e0 += exp2g(acc0[r]);     e1 += exp2g(acc0[r + 1]);
                    e2 += exp2g(acc0[r + 2]); e3 += exp2g(acc0[r + 3]);
                }
                srun0 += (e0 + e1) + (e2 + e3);
            }
            {
                float e0 = 0, e1 = 0, e2 = 0, e3 = 0;
                #pragma unroll
                for (int r = 0; r < 16; r += 4) {
                    e0 += exp2g(acc1[r]);     e1 += exp2g(acc1[r + 1]);
                    e2 += exp2g(acc1[r + 2]); e3 += exp2g(acc1[r + 3]);
                }
                srun1 += (e0 + e1) + (e2 + e3);
            }
        }

        __syncthreads();   // one barrier per 64-n tile (4 total vs R11's 8)
    }

    // combine kg halves; one writer per m-col (wave owns its cols exclusively)
    srun0 += __shfl_xor(srun0, 32);
    srun1 += __shfl_xor(srun1, 32);
    if (kg == 0) {
        ws_sum[(b * 8 + ns) * NN + mcol0] = srun0;
        ws_sum[(b * 8 + ns) * NN + mcol1] = srun1;
    }
}

__global__ __launch_bounds__(256) void merge_kernel(
    const float* __restrict__ ws_sum, const float* __restrict__ ws_diag,
    float* __restrict__ partial)
{
    const int gid = blockIdx.x * 256 + threadIdx.x;   // 0..16383
    const int b = gid >> 11, m = gid & (NN - 1);

    float S = 0.0f;
    #pragma unroll
    for (int slot = 0; slot < 8; ++slot)
        S += ws_sum[(b * 8 + slot) * NN + m];
    float c = log2g(S) - ws_diag[gid];   // (LSE' - diag') in log2 units

    #pragma unroll
    for (int d = 1; d < 64; d <<= 1) c += __shfl_xor(c, d);
    __shared__ float red[4];
    if ((threadIdx.x & 63) == 0) red[threadIdx.x >> 6] = c;
    __syncthreads();
    if (threadIdx.x == 0)
        partial[blockIdx.x] = red[0] + red[1] + red[2] + red[3];
}

__global__ void final_kernel(const float* __restrict__ partial, float* __restrict__ out)
{
    float v = partial[threadIdx.x];   // 64 threads
    #pragma unroll
    for (int d = 1; d < 64; d <<= 1) v += __shfl_xor(v, d);
    if (threadIdx.x == 0) out[0] = v * (LN2 / 16384.0f);
}

extern "C" void kernel_launch(void* const* d_in, const int* in_sizes, int n_in,
                              void* d_out, int out_size, void* d_ws, size_t ws_size,
                              hipStream_t stream)
{
    const float* z1 = (const float*)d_in[0];
    const float* z2 = (const float*)d_in[1];
    float* ws  = (float*)d_ws;
    float* out = (float*)d_out;

    // ws layout (floats): sum[8][8][2048] | diag[8][2048] | partial[64]
    float* ws_sum  = ws;
    float* ws_diag = ws + 131072;
    float* ws_part = ws + 147456;

    gemm_lse_kernel<<<dim3(256), dim3(512), 0, stream>>>(z1, z2, ws_sum, ws_diag);
    merge_kernel<<<dim3(64), dim3(256), 0, stream>>>(ws_sum, ws_diag, ws_part);
    final_kernel<<<dim3(1), dim3(64), 0, stream>>>(ws_part, out);
}

// Round 15
// 29.106 us; speedup vs baseline: 2.6386x; 2.6386x over previous
//
#include <hip/hip_runtime.h>
#include <hip/hip_bf16.h>

// BarlowTwins loss: logits[b,n,m] = sum_s z1[b,s,n]*z2[b,s,m]  (B=8, S=256, N=M=2048)
// loss = mean_{b,m}( LSE_n(logits[b,:,m]) - logits[b,m,m] )
//
// Round-15 = R11's decomposition (block 512m x 256n, wave owns 64m (2 strips, bf 128
// regs) x full 256n, grid 256 = 1 block/CU lockstep, exp2-sum no max tracking) with
// SINGLE MEGA-STAGE: the whole 256n x 256k A panel goes to LDS once (stride 264,
// 132KB of the 160KB CU budget), ONE barrier, then 8 subtiles of pure
// {16 ds_read_b128 + 32 MFMA + 32 exp2} with NO barriers -- waves desync and the
// 2 waves/SIMD anti-align across pipes (m114). Removes R11's 8 lockstep barrier
// drains + dbuf staging interleave (the m233 2-phase stall).
// Bank math (stride 264 = 33 x 16B slots): write slot = row+2kg (2-way), read slot =
// col+2ks+kg (2-way) -> both free; same scheme as R2/R4/R11 (measured 0 conflicts).

#define NN 2048
#define SK 256
#define LDST 264
#define LOG2E 1.4426950408889634f
#define LN2   0.6931471805599453f
#define COFF  96.0f

typedef __attribute__((ext_vector_type(8))) short short8;
typedef __attribute__((ext_vector_type(16))) float f32x16;

__device__ __forceinline__ unsigned short f2bf(float f) {
    __hip_bfloat16 h = __float2bfloat16(f);
    unsigned short u; __builtin_memcpy(&u, &h, 2); return u;
}

__device__ __forceinline__ float exp2g(float x) {
#if __has_builtin(__builtin_amdgcn_exp2f)
    return __builtin_amdgcn_exp2f(x);
#else
    return exp2f(x);
#endif
}

__device__ __forceinline__ float log2g(float x) {
#if __has_builtin(__builtin_amdgcn_logf)
    return __builtin_amdgcn_logf(x);
#else
    return log2f(x);
#endif
}

__global__ __launch_bounds__(512) void gemm_lse_kernel(
    const float* __restrict__ z1, const float* __restrict__ z2,
    float* __restrict__ ws_sum, float* __restrict__ ws_diag)
{
    __shared__ unsigned short lds[256 * LDST];   // 132 KB: whole 256n x 256k panel

    const int bid  = blockIdx.x;
    const int b    = bid & 7;          // XCD-aligned batch
    const int tile = bid >> 3;
    const int mb   = tile & 3;         // 4 m-blocks of 512
    const int ns   = tile >> 2;        // 8 n-splits of 256
    const int tid  = threadIdx.x;
    const int lane = tid & 63;
    const int w    = tid >> 6;         // wave 0..7 owns 64 m
    const int col  = lane & 31;
    const int kg   = lane >> 5;

    const int m0      = mb * 512 + w * 64;   // strip0; strip1 = +32
    const int mcol0   = m0 + col;
    const int mcol1   = m0 + 32 + col;
    const int n_start = ns * 256;

    const float* z1b = z1 + (size_t)b * SK * NN;
    const float* z2b = z2 + (size_t)b * SK * NN;

    // ---- mega-stage: thread (kc,row) stages 8 rows x 16 s of the 256x256 panel ----
    const int kc  = (w << 1) | kg;     // k-chunk 0..15 (16 s each)
    const int row = col;               // base n-row
    #pragma unroll
    for (int rg = 0; rg < 8; ++rg) {
        const int nrow = rg * 32 + row;
        const float* p = z1b + (size_t)(kc * 16) * NN + (n_start + nrow);
        float t0[8], t1[8];
        #pragma unroll
        for (int j = 0; j < 8; ++j) t0[j] = p[(size_t)j * NN];
        #pragma unroll
        for (int j = 0; j < 8; ++j) t1[j] = p[(size_t)(j + 8) * NN];
        short8 pk0, pk1;
        #pragma unroll
        for (int j = 0; j < 8; ++j) { pk0[j] = (short)f2bf(t0[j]); pk1[j] = (short)f2bf(t1[j]); }
        *(short8*)(lds + nrow * LDST + kc * 16)     = pk0;
        *(short8*)(lds + nrow * LDST + kc * 16 + 8) = pk1;
    }

    // ---- B fragments: 2 strips x K=256, coalesced f32 column loads, x log2e ----
    short8 bf0[16], bf1[16];
    #pragma unroll
    for (int ks = 0; ks < 16; ++ks) {
        short8 p0, p1;
        #pragma unroll
        for (int j = 0; j < 8; ++j) {
            const int s = ks * 16 + kg * 8 + j;
            p0[j] = (short)f2bf(z2b[(size_t)s * NN + mcol0] * LOG2E);
            p1[j] = (short)f2bf(z2b[(size_t)s * NN + mcol1] * LOG2E);
        }
        bf0[ks] = p0; bf1[ks] = p1;
    }

    float srun0 = 0.0f, srun1 = 0.0f;

    __syncthreads();   // the ONLY barrier: panel + B landed

    #pragma unroll 2
    for (int sub = 0; sub < 8; ++sub) {
        const unsigned short* abase = lds + (32 * sub + col) * LDST + kg * 8;

        f32x16 acc0, acc1;
        #pragma unroll
        for (int r = 0; r < 16; ++r) { acc0[r] = -COFF; acc1[r] = -COFF; }

        #pragma unroll
        for (int ks = 0; ks < 16; ++ks) {
            short8 af = *(const short8*)(abase + ks * 16);
            acc0 = __builtin_amdgcn_mfma_f32_32x32x16_bf16(af, bf0[ks], acc0, 0, 0, 0);
            acc1 = __builtin_amdgcn_mfma_f32_32x32x16_bf16(af, bf1[ks], acc1, 0, 0, 0);
        }

        // diagonal capture (acc = logit' - 96; offset cancels in merge)
        const int nsub = n_start + 32 * sub;
        if (nsub == m0) {
            #pragma unroll
            for (int r = 0; r < 16; ++r) {
                const int rw = (r & 3) + 8 * (r >> 2) + 4 * kg;
                if (rw == col) ws_diag[b * NN + mcol0] = acc0[r];
            }
        }
        if (nsub == m0 + 32) {
            #pragma unroll
            for (int r = 0; r < 16; ++r) {
                const int rw = (r & 3) + 8 * (r >> 2) + 4 * kg;
                if (rw == col) ws_diag[b * NN + mcol1] = acc1[r];
            }
        }

        // exp2-sum, 4 independent chains per strip
        {
            float e0 = 0, e1 = 0, e2 = 0, e3 = 0;
            #pragma unroll
            for (int r = 0; r < 16; r += 4) {
                e0 += exp2g(acc0[r]);     e1 += exp2g(acc0[r + 1]);
                e2 += exp2g(acc0[r + 2]); e3 += exp2g(acc0[r + 3]);
            }
            srun0 += (e0 + e1) + (e2 + e3);
        }
        {
            float e0 = 0, e1 = 0, e2 = 0, e3 = 0;
            #pragma unroll
            for (int r = 0; r < 16; r += 4) {
                e0 += exp2g(acc1[r]);     e1 += exp2g(acc1[r + 1]);
                e2 += exp2g(acc1[r + 2]); e3 += exp2g(acc1[r + 3]);
            }
            srun1 += (e0 + e1) + (e2 + e3);
        }
    }

    // combine kg halves; one writer per m-col (wave owns its cols exclusively)
    srun0 += __shfl_xor(srun0, 32);
    srun1 += __shfl_xor(srun1, 32);
    if (kg == 0) {
        ws_sum[(b * 8 + ns) * NN + mcol0] = srun0;
        ws_sum[(b * 8 + ns) * NN + mcol1] = srun1;
    }
}

__global__ __launch_bounds__(256) void merge_kernel(
    const float* __restrict__ ws_sum, const float* __restrict__ ws_diag,
    float* __restrict__ partial)
{
    const int gid = blockIdx.x * 256 + threadIdx.x;   // 0..16383
    const int b = gid >> 11, m = gid & (NN - 1);

    float S = 0.0f;
    #pragma unroll
    for (int slot = 0; slot < 8; ++slot)
        S += ws_sum[(b * 8 + slot) * NN + m];
    float c = log2g(S) - ws_diag[gid];   // (LSE' - diag') in log2 units

    #pragma unroll
    for (int d = 1; d < 64; d <<= 1) c += __shfl_xor(c, d);
    __shared__ float red[4];
    if ((threadIdx.x & 63) == 0) red[threadIdx.x >> 6] = c;
    __syncthreads();
    if (threadIdx.x == 0)
        partial[blockIdx.x] = red[0] + red[1] + red[2] + red[3];
}

__global__ void final_kernel(const float* __restrict__ partial, float* __restrict__ out)
{
    float v = partial[threadIdx.x];   // 64 threads
    #pragma unroll
    for (int d = 1; d < 64; d <<= 1) v += __shfl_xor(v, d);
    if (threadIdx.x == 0) out[0] = v * (LN2 / 16384.0f);
}

extern "C" void kernel_launch(void* const* d_in, const int* in_sizes, int n_in,
                              void* d_out, int out_size, void* d_ws, size_t ws_size,
                              hipStream_t stream)
{
    const float* z1 = (const float*)d_in[0];
    const float* z2 = (const float*)d_in[1];
    float* ws  = (float*)d_ws;
    float* out = (float*)d_out;

    // ws layout (floats): sum[8][8][2048] | diag[8][2048] | partial[64]
    float* ws_sum  = ws;
    float* ws_diag = ws + 131072;
    float* ws_part = ws + 147456;

    gemm_lse_kernel<<<dim3(256), dim3(512), 0, stream>>>(z1, z2, ws_sum, ws_diag);
    merge_kernel<<<dim3(64), dim3(256), 0, stream>>>(ws_sum, ws_diag, ws_part);
    final_kernel<<<dim3(1), dim3(64), 0, stream>>>(ws_part, out);
}